// Round 21
// baseline (126.100 us; speedup 1.0000x reference)
//
#include <hip/hip_runtime.h>
#include <cstdint>
#include <cstddef>
#include <cmath>

// ---------------------------------------------------------------------------
// MultiHeadAttention (B=2, S=2048, DIM=1024, H=16, HD=64), causal + RoPE.
// R21 = R20 + attn rewritten on 32x32x16 MFMA: 128-thread blocks (2 waves x
// 32 q-rows), swapped QK^T (q = lane&31 -> row spread over 2 lanes only:
// softmax = 31 in-lane ops + 1 shfl), half the MFMA instructions per FLOP.
// Same K/V tiles, swizzles, sync staging, defer-max, descending dispatch.
// GEMMs/prep byte-identical to R20 (passing, 115.0us).
// ---------------------------------------------------------------------------

typedef __bf16 bf16_t;
typedef __bf16 bf16x8 __attribute__((ext_vector_type(8)));
typedef __bf16 bf16x4 __attribute__((ext_vector_type(4)));
typedef float  f32x4  __attribute__((ext_vector_type(4)));
typedef float  f32x16 __attribute__((ext_vector_type(16)));

#define DEVFN __device__ __forceinline__

static constexpr int Bn  = 2;
static constexpr int S   = 2048;
static constexpr int DIM = 1024;
static constexpr int NH  = 16;
static constexpr int HD  = 64;
static constexpr int Mrows = Bn * S;        // 4096

DEVFN f32x4 mfma16(bf16x8 a, bf16x8 b, f32x4 c) {
  return __builtin_amdgcn_mfma_f32_16x16x32_bf16(a, b, c, 0, 0, 0);
}
DEVFN f32x16 mfma32(bf16x8 a, bf16x8 b, f32x16 c) {
  return __builtin_amdgcn_mfma_f32_32x32x16_bf16(a, b, c, 0, 0, 0);
}

DEVFN void gl_lds16(const bf16_t* g, bf16_t* l) {
  __builtin_amdgcn_global_load_lds(
      (const __attribute__((address_space(1))) unsigned*)g,
      (__attribute__((address_space(3))) unsigned*)l, 16, 0, 0);
}

DEVFN float fast_exp2(float x) { return exp2f(x); }  // -> v_exp_f32

// ---------------------------------------------------------------------------
// One launch: all fp32->bf16 converts + rope table.
__global__ __launch_bounds__(256) void k_prep(
    const float* __restrict__ x, const float* __restrict__ wq,
    const float* __restrict__ wk, const float* __restrict__ wv,
    const float* __restrict__ wo, bf16_t* __restrict__ xb,
    bf16_t* __restrict__ wqb, bf16_t* __restrict__ wkb,
    bf16_t* __restrict__ wvb, bf16_t* __restrict__ wob,
    float2* __restrict__ tab) {
  const int bid = blockIdx.x;
  if (bid < 8192) {
    const float* src;
    bf16_t* dst;
    size_t base;
    if (bid < 4096) {
      src = x; dst = xb; base = (size_t)bid << 10;
    } else {
      int wsel = (bid - 4096) >> 10;
      src = wsel == 0 ? wq : wsel == 1 ? wk : wsel == 2 ? wv : wo;
      dst = wsel == 0 ? wqb : wsel == 1 ? wkb : wsel == 2 ? wvb : wob;
      base = (size_t)((bid - 4096) & 1023) << 10;
    }
    size_t i = base + (size_t)threadIdx.x * 4;
    float4 v = *(const float4*)(src + i);
    bf16x4 o = { (bf16_t)v.x, (bf16_t)v.y, (bf16_t)v.z, (bf16_t)v.w };
    *(bf16x4*)(dst + i) = o;
  } else {
    int i = (bid - 8192) * 256 + threadIdx.x;  // < S*32
    int s = i >> 5, d = i & 31;
    float th = (float)s * expf((float)d * -0.2878231366f);  // ln(10000)/32
    tab[i] = make_float2(cosf(th), sinf(th));
  }
}

// ---------------------------------------------------------------------------
// Fused QKV NT GEMM (byte-identical to R20): 128x64 tiles, 1536 blocks.
// z=0 Q (rope, 0.125*log2e), z=1 K (rope), z=2 V (transposed into VT).
__global__ __launch_bounds__(256) void k_gemm_qkv(
    const bf16_t* __restrict__ A, const bf16_t* __restrict__ Wall,
    const float* __restrict__ c0, const float* __restrict__ c1,
    const float* __restrict__ c2, bf16_t* __restrict__ Oq,
    bf16_t* __restrict__ Ok, bf16_t* __restrict__ VTo,
    const float2* __restrict__ tab) {
  __shared__ __align__(16) bf16_t Al[128 * 64];
  __shared__ __align__(16) bf16_t Bl[64 * 64];
  const int t = threadIdx.x, w = t >> 6, l = t & 63;
  const int lr = l & 15, lc = l >> 4;
  const int lid = blockIdx.x;                     // 1536 blocks
  const int xcd = lid & 7, s = lid >> 3;          // s in [0,192)
  const int my = ((xcd >> 1) << 3) + (s & 7);     // [0,32)
  const int nx = (xcd & 1) * 24 + (s >> 3);       // [0,48)
  const int m0 = my * 128, n0g = nx * 64;
  const int z = n0g >> 10, n0l = n0g & 1023;
  f32x4 acc[2][4] = {};

  for (int k0 = 0; k0 < DIM; k0 += 64) {
    __syncthreads();
#pragma unroll
    for (int ld = 0; ld < 4; ++ld) {
      int c = t + ld * 256;
      int row = c >> 3;
      int j = ((c & 7) ^ (row & 7)) << 3;
      gl_lds16(A + (size_t)(m0 + row) * DIM + k0 + j,
               Al + (size_t)(w * 64 + ld * 256) * 8);
    }
#pragma unroll
    for (int ld = 0; ld < 2; ++ld) {
      int c = t + ld * 256;
      int row = c >> 3;
      int j = ((c & 7) ^ (row & 7)) << 3;
      gl_lds16(Wall + (size_t)(n0g + row) * DIM + k0 + j,
               Bl + (size_t)(w * 64 + ld * 256) * 8);
    }
    asm volatile("s_waitcnt vmcnt(0)" ::: "memory");
    __syncthreads();
    bf16x8 af[2][2], bfr[2][4];
#pragma unroll
    for (int ks = 0; ks < 2; ++ks) {
#pragma unroll
      for (int mi = 0; mi < 2; ++mi) {
        int row = w * 32 + mi * 16 + lr;
        int off = ((ks * 4 + lc) << 4) ^ ((row & 7) << 4);
        af[ks][mi] = *(const bf16x8*)((const char*)Al + row * 128 + off);
      }
#pragma unroll
      for (int ni = 0; ni < 4; ++ni) {
        int row = ni * 16 + lr;
        int off = ((ks * 4 + lc) << 4) ^ ((row & 7) << 4);
        bfr[ks][ni] = *(const bf16x8*)((const char*)Bl + row * 128 + off);
      }
    }
    __builtin_amdgcn_s_setprio(1);
#pragma unroll
    for (int ks = 0; ks < 2; ++ks)
#pragma unroll
      for (int mi = 0; mi < 2; ++mi)
#pragma unroll
        for (int ni = 0; ni < 4; ++ni)
          acc[mi][ni] = mfma16(af[ks][mi], bfr[ks][ni], acc[mi][ni]);
    __builtin_amdgcn_s_setprio(0);
  }

  if (z == 2) {
    const int h = n0l >> 6;
#pragma unroll
    for (int ni = 0; ni < 4; ++ni) {
      const int d = ni * 16 + lr;
      const float bv = c2[n0l + ni * 16 + lr];
#pragma unroll
      for (int mi = 0; mi < 2; ++mi) {
        int rowb = m0 + w * 32 + mi * 16 + lc * 4;
        int bb = rowb >> 11, ss = rowb & (S - 1);
        bf16x4 pb = { (bf16_t)(acc[mi][ni][0] + bv),
                      (bf16_t)(acc[mi][ni][1] + bv),
                      (bf16_t)(acc[mi][ni][2] + bv),
                      (bf16_t)(acc[mi][ni][3] + bv) };
        *(bf16x4*)(VTo + ((size_t)(bb * NH + h) * HD + d) * S + ss) = pb;
      }
    }
  } else {
    bf16_t* Ov = z == 0 ? Oq : Ok;
    const float* bias = z == 0 ? c0 : c1;
    const float scale = z == 0 ? 0.125f * 1.4426950408889634f : 1.0f;
#pragma unroll
    for (int ni = 0; ni < 4; ++ni) {
      const int col = n0l + ni * 16 + lr;
      const float bv = bias[col];
      const int p0 = ni * 8 + (lr >> 1);
#pragma unroll
      for (int mi = 0; mi < 2; ++mi) {
#pragma unroll
        for (int r = 0; r < 4; ++r) {
          int row = m0 + w * 32 + mi * 16 + lc * 4 + r;
          float v = acc[mi][ni][r] + bv;
          float pt = __shfl_xor(v, 1);
          float2 cs = tab[(row & (S - 1)) * 32 + p0];
          float out = (lr & 1) ? (pt * cs.y + v * cs.x)
                               : (v * cs.x - pt * cs.y);
          Ov[(size_t)row * DIM + col] = (bf16_t)(out * scale);
        }
      }
    }
  }
}

// ---------------------------------------------------------------------------
// Out projection (byte-identical to R20): 64x64 tiles, 1024 blocks.
__global__ __launch_bounds__(256) void k_gemm_out(
    const bf16_t* __restrict__ A, const bf16_t* __restrict__ Bw,
    const float* __restrict__ bias, float* __restrict__ Ov) {
  __shared__ __align__(16) bf16_t Al[64 * 64];
  __shared__ __align__(16) bf16_t Bl[64 * 64];
  const int t = threadIdx.x, w = t >> 6, l = t & 63;
  const int lr = l & 15, lc = l >> 4;
  const int lid = blockIdx.x;                     // 1024 blocks
  const int xcd = lid & 7, s = lid >> 3;          // s in [0,128)
  const int my = ((xcd >> 1) << 4) + (s & 15);    // [0,64)
  const int nx = (xcd & 1) * 8 + (s >> 4);        // [0,16)
  const int m0 = my * 64, n0 = nx * 64;
  f32x4 acc[4] = {};

  for (int k0 = 0; k0 < DIM; k0 += 64) {
    __syncthreads();
#pragma unroll
    for (int ld = 0; ld < 2; ++ld) {
      int c = t + ld * 256;
      int row = c >> 3;
      int j = ((c & 7) ^ (row & 7)) << 3;
      gl_lds16(A + (size_t)(m0 + row) * DIM + k0 + j,
               Al + (size_t)(w * 64 + ld * 256) * 8);
    }
#pragma unroll
    for (int ld = 0; ld < 2; ++ld) {
      int c = t + ld * 256;
      int row = c >> 3;
      int j = ((c & 7) ^ (row & 7)) << 3;
      gl_lds16(Bw + (size_t)(n0 + row) * DIM + k0 + j,
               Bl + (size_t)(w * 64 + ld * 256) * 8);
    }
    asm volatile("s_waitcnt vmcnt(0)" ::: "memory");
    __syncthreads();
    bf16x8 af[2], bfr[2][4];
#pragma unroll
    for (int ks = 0; ks < 2; ++ks) {
      int arow = w * 16 + lr;
      int aoff = ((ks * 4 + lc) << 4) ^ ((arow & 7) << 4);
      af[ks] = *(const bf16x8*)((const char*)Al + arow * 128 + aoff);
#pragma unroll
      for (int ni = 0; ni < 4; ++ni) {
        int row = ni * 16 + lr;
        int off = ((ks * 4 + lc) << 4) ^ ((row & 7) << 4);
        bfr[ks][ni] = *(const bf16x8*)((const char*)Bl + row * 128 + off);
      }
    }
    __builtin_amdgcn_s_setprio(1);
#pragma unroll
    for (int ks = 0; ks < 2; ++ks)
#pragma unroll
      for (int ni = 0; ni < 4; ++ni)
        acc[ni] = mfma16(af[ks], bfr[ks][ni], acc[ni]);
    __builtin_amdgcn_s_setprio(0);
  }

#pragma unroll
  for (int ni = 0; ni < 4; ++ni) {
    int col = n0 + ni * 16 + lr;
    float bv = bias[col];
#pragma unroll
    for (int r = 0; r < 4; ++r) {
      int row = m0 + w * 16 + lc * 4 + r;
      Ov[(size_t)row * DIM + col] = acc[ni][r] + bv;
    }
  }
}

// ---------------------------------------------------------------------------
// Causal flash attention, R21: 32x32x16 MFMA. 128-thread blocks (2 waves x
// 32 q-rows), one 64-q tile per block, grid 1024, descending dispatch.
// KVBLK=64, single-buffered sync staging. Swapped QK^T: D col=lane&31 = q,
// row=(reg&3)+8*(reg>>2)+4*hi = kv -> q-row on 2 lanes; softmax is 31
// in-lane ops + 1 shfl_xor(32). P through LDS [32q][64kv] per wave.
DEVFN void stage_kv128(const bf16_t* __restrict__ Kc,
                       const bf16_t* __restrict__ VT, bf16_t* Kb, bf16_t* Vb,
                       int b, int bh, int h, int k0, int tid, int w) {
#pragma unroll
  for (int ld = 0; ld < 4; ++ld) {
    int c = tid + ld * 128;              // 0..511
    int row = c >> 3;
    int j = ((c & 7) ^ (row & 7)) << 3;  // pre-swizzled source chunk
    bf16_t* dstK = Kb + (size_t)(w * 64 + ld * 128) * 8;
    bf16_t* dstV = Vb + (size_t)(w * 64 + ld * 128) * 8;
    gl_lds16(Kc + (size_t)(b * S + k0 + row) * DIM + h * HD + j, dstK);
    gl_lds16(VT + ((size_t)bh * HD + row) * S + k0 + j, dstV);
  }
}

__global__ __launch_bounds__(128) void k_attn(const bf16_t* __restrict__ Q,
                                              const bf16_t* __restrict__ Kc,
                                              const bf16_t* __restrict__ VT,
                                              bf16_t* __restrict__ O) {
  __shared__ __align__(16) bf16_t Kl[64 * 64];      // [kv][d]
  __shared__ __align__(16) bf16_t Vl[64 * 64];      // [d][kv]
  __shared__ __align__(16) bf16_t Pl[2][32 * 64];   // per wave [q][kv]
  const int tid = threadIdx.x, w = tid >> 6, l = tid & 63;
  const int l31 = l & 31, hi = l >> 5;
  const int lid = blockIdx.x;
  const int xcd = lid & 7;
  const int rest = lid >> 3;          // 0..127
  const int t_ord = rest >> 2;        // 0..31
  const int hh = rest & 3;
  const int tile = 31 - t_ord;        // big tiles dispatch first
  const int bh = xcd * 4 + hh;
  const int b = bh >> 4, h = bh & 15;
  char* Pw = (char*)&Pl[w][0];
  const int swz = (l31 & 7) << 4;     // row-XOR for q/kv/d rows (=row&7<<4)

  const int q0 = tile * 64;
  const int nt = tile + 1;
  const int qg = q0 + w * 32 + l31;   // this lane's q row (global)

  bf16x8 qf[4];
  {
    const bf16_t* qp = Q + (size_t)(b * S + qg) * DIM + h * HD + hi * 8;
    qf[0] = *(const bf16x8*)qp;
    qf[1] = *(const bf16x8*)(qp + 16);
    qf[2] = *(const bf16x8*)(qp + 32);
    qf[3] = *(const bf16x8*)(qp + 48);
  }
  f32x16 o0 = {}, o1 = {};            // nsub 0/1: d = nsub*32 + l31... no:
                                      // o col = d-half; see PV below.
  float m_run = -INFINITY;
  float rowsum = 0.f;

#pragma unroll 1
  for (int it = 0; it < nt; ++it) {
    stage_kv128(Kc, VT, &Kl[0], &Vl[0], b, bh, h, it * 64, tid, w);
    asm volatile("s_waitcnt vmcnt(0)" ::: "memory");
    __builtin_amdgcn_s_barrier();
    __builtin_amdgcn_sched_barrier(0);

    // swapped QK^T: s_ns[reg] = S'[q=l31][kv=ns*32+(reg&3)+8*(reg>>2)+4*hi]
    f32x16 s0 = {}, s1 = {};
    __builtin_amdgcn_s_setprio(1);
#pragma unroll
    for (int t = 0; t < 4; ++t) {
      int boff = t * 32 + hi * 16;    // byte offset for d = t*16 + hi*8
      bf16x8 kf0 = *(const bf16x8*)((const char*)Kl + l31 * 128 +
                                    (boff ^ swz));
      bf16x8 kf1 = *(const bf16x8*)((const char*)Kl + (32 + l31) * 128 +
                                    (boff ^ swz));
      s0 = mfma32(kf0, qf[t], s0);
      s1 = mfma32(kf1, qf[t], s1);
    }
    __builtin_amdgcn_s_setprio(0);

    if (it == tile) {  // diagonal tile: mask kv_local > q_local
      const int qloc = w * 32 + l31;
#pragma unroll
      for (int reg = 0; reg < 16; ++reg) {
        int kvr = (reg & 3) + 8 * (reg >> 2) + 4 * hi;
        if (kvr > qloc) s0[reg] = -INFINITY;
        if (32 + kvr > qloc) s1[reg] = -INFINITY;
      }
    }

    // row max: 31 in-lane + 1 cross-half
    float pm = s0[0];
#pragma unroll
    for (int reg = 1; reg < 16; ++reg) pm = fmaxf(pm, s0[reg]);
#pragma unroll
    for (int reg = 0; reg < 16; ++reg) pm = fmaxf(pm, s1[reg]);
    pm = fmaxf(pm, __shfl_xor(pm, 32));

    // defer-max (log2 units)
    if (__ballot(pm > m_run + 8.f)) {
      float mn = fmaxf(m_run, pm);
      float alpha = fast_exp2(m_run - mn);
      m_run = mn;
      rowsum *= alpha;
#pragma unroll
      for (int reg = 0; reg < 16; ++reg) {
        int qrow = (reg & 3) + 8 * (reg >> 2) + 4 * hi;
        float aq = __shfl(alpha, qrow);
        o0[reg] *= aq;
        o1[reg] *= aq;
      }
    }

    // P = exp2(s - m); pack b64 into Pl[q][kv] (kv groups of 4 consecutive)
    float rs = 0.f;
#pragma unroll
    for (int g = 0; g < 4; ++g) {
      float a0 = fast_exp2(s0[4 * g + 0] - m_run);
      float a1 = fast_exp2(s0[4 * g + 1] - m_run);
      float a2 = fast_exp2(s0[4 * g + 2] - m_run);
      float a3 = fast_exp2(s0[4 * g + 3] - m_run);
      rs += (a0 + a1) + (a2 + a3);
      bf16x4 pb = { (bf16_t)a0, (bf16_t)a1, (bf16_t)a2, (bf16_t)a3 };
      *(bf16x4*)(Pw + l31 * 128 + ((g * 16 + hi * 8) ^ swz)) = pb;
      float b0 = fast_exp2(s1[4 * g + 0] - m_run);
      float b1 = fast_exp2(s1[4 * g + 1] - m_run);
      float b2 = fast_exp2(s1[4 * g + 2] - m_run);
      float b3 = fast_exp2(s1[4 * g + 3] - m_run);
      rs += (b0 + b1) + (b2 + b3);
      bf16x4 qb = { (bf16_t)b0, (bf16_t)b1, (bf16_t)b2, (bf16_t)b3 };
      *(bf16x4*)(Pw + l31 * 128 + ((64 + g * 16 + hi * 8) ^ swz)) = qb;
    }
    rs += __shfl_xor(rs, 32);
    rowsum += rs;

    // PV: o_nsub[reg] holds O[q=(reg&3)+8*(reg>>2)+4*hi][d=nsub*32+l31]
    __builtin_amdgcn_s_setprio(1);
#pragma unroll
    for (int ns = 0; ns < 2; ++ns)
#pragma unroll
      for (int t = 0; t < 2; ++t) {
        int pboff = ns * 64 + t * 32 + hi * 16;  // kv = ns*32+t*16+hi*8
        bf16x8 pa = *(const bf16x8*)(Pw + l31 * 128 + (pboff ^ swz));
        bf16x8 v0 = *(const bf16x8*)((const char*)Vl + l31 * 128 +
                                     (pboff ^ swz));
        bf16x8 v1 = *(const bf16x8*)((const char*)Vl + (32 + l31) * 128 +
                                     (pboff ^ swz));
        o0 = mfma32(pa, v0, o0);
        o1 = mfma32(pa, v1, o1);
      }
    __builtin_amdgcn_s_setprio(0);

    __builtin_amdgcn_s_barrier();  // all reads done before next stage
  }

  // normalize + store: q = q0 + w*32 + (reg&3)+8*(reg>>2)+4*hi, d = nsub*32+l31
#pragma unroll
  for (int reg = 0; reg < 16; ++reg) {
    int qrow = (reg & 3) + 8 * (reg >> 2) + 4 * hi;
    float inv = 1.0f / __shfl(rowsum, qrow);
    int qr = q0 + w * 32 + qrow;
    bf16_t* op = O + (size_t)(b * S + qr) * DIM + h * HD + l31;
    op[0]  = (bf16_t)(o0[reg] * inv);
    op[32] = (bf16_t)(o1[reg] * inv);
  }
}

// ---------------------------------------------------------------------------
extern "C" void kernel_launch(void* const* d_in, const int* in_sizes, int n_in,
                              void* d_out, int out_size, void* d_ws,
                              size_t ws_size, hipStream_t stream) {
  const float* x  = (const float*)d_in[0];
  const float* wq = (const float*)d_in[1];
  const float* bq = (const float*)d_in[2];
  const float* wk = (const float*)d_in[3];
  const float* bk = (const float*)d_in[4];
  const float* wv = (const float*)d_in[5];
  const float* bv = (const float*)d_in[6];
  const float* wo = (const float*)d_in[7];
  const float* bo = (const float*)d_in[8];

  const size_t MD = (size_t)Mrows * DIM;   // 4194304
  const size_t WD = (size_t)DIM * DIM;     // 1048576
  bf16_t* W = (bf16_t*)d_ws;
  bf16_t* x_bf  = W;
  bf16_t* wq_bf = x_bf + MD;               // wq|wk|wv contiguous = [3072][1024]
  bf16_t* wk_bf = wq_bf + WD;
  bf16_t* wv_bf = wk_bf + WD;
  bf16_t* wo_bf = wv_bf + WD;
  bf16_t* q_lin = wo_bf + WD;
  bf16_t* k_lin = q_lin + MD;
  bf16_t* v_lin = k_lin + MD;              // unused (kept for layout)
  bf16_t* vT    = v_lin + MD;
  float2* tab   = (float2*)(vT + MD);
  bf16_t* attn_out = x_bf;  // x_bf dead after k_gemm_qkv; rewritten by k_prep
                            // every call -> no cross-call state dependency

  k_prep<<<8448, 256, 0, stream>>>(x, wq, wk, wv, wo, x_bf, wq_bf, wk_bf,
                                   wv_bf, wo_bf, tab);

  // Q/K leave already roped (Q scaled 1/8*log2e); V leaves transposed in VT.
  k_gemm_qkv<<<1536, 256, 0, stream>>>(x_bf, wq_bf, bq, bk, bv, q_lin, k_lin,
                                       vT, tab);

  k_attn<<<1024, 128, 0, stream>>>(q_lin, k_lin, vT, attn_out);

  k_gemm_out<<<1024, 256, 0, stream>>>(attn_out, wo_bf, bo, (float*)d_out);
}

// Round 22
// 113.927 us; speedup vs baseline: 1.1069x; 1.1069x over previous
//
#include <hip/hip_runtime.h>
#include <cstdint>
#include <cstddef>
#include <cmath>

// ---------------------------------------------------------------------------
// MultiHeadAttention (B=2, S=2048, DIM=1024, H=16, HD=64), causal + RoPE.
// R22 = exact revert to R20 (best: 115.0 us). R21's 32x32-MFMA attn passed
// correctness but regressed (8 waves/CU vs 16; bank conflicts 3.5x). The
// lever record is now complete: occupancy/fusion wins are harvested, all
// remaining structural ideas measured negative. Converged state:
//   k_prep     : fp32->bf16 x5 + rope table (1 launch)
//   k_gemm_qkv : fused N=3072 NT GEMM, 128x64 tiles, 1536 blocks; epilogue
//                applies RoPE (Q scaled 1/8*log2e, K) and V-transpose to VT
//   k_attn     : causal flash attn, KVBLK=64, grid 1024 (4 blocks/CU),
//                swapped QK^T + exp2 softmax + defer-max, descending dispatch
//   k_gemm_out : 64x64 tiles, 1024 blocks, fp32+bias into d_out
// ---------------------------------------------------------------------------

typedef __bf16 bf16_t;
typedef __bf16 bf16x8 __attribute__((ext_vector_type(8)));
typedef __bf16 bf16x4 __attribute__((ext_vector_type(4)));
typedef float  f32x4  __attribute__((ext_vector_type(4)));

#define DEVFN __device__ __forceinline__

static constexpr int Bn  = 2;
static constexpr int S   = 2048;
static constexpr int DIM = 1024;
static constexpr int NH  = 16;
static constexpr int HD  = 64;
static constexpr int Mrows = Bn * S;        // 4096

DEVFN f32x4 mfma16(bf16x8 a, bf16x8 b, f32x4 c) {
  return __builtin_amdgcn_mfma_f32_16x16x32_bf16(a, b, c, 0, 0, 0);
}

DEVFN void gl_lds16(const bf16_t* g, bf16_t* l) {
  __builtin_amdgcn_global_load_lds(
      (const __attribute__((address_space(1))) unsigned*)g,
      (__attribute__((address_space(3))) unsigned*)l, 16, 0, 0);
}

DEVFN float fast_exp2(float x) { return exp2f(x); }  // -> v_exp_f32

// ---------------------------------------------------------------------------
// One launch: all fp32->bf16 converts + rope table.
__global__ __launch_bounds__(256) void k_prep(
    const float* __restrict__ x, const float* __restrict__ wq,
    const float* __restrict__ wk, const float* __restrict__ wv,
    const float* __restrict__ wo, bf16_t* __restrict__ xb,
    bf16_t* __restrict__ wqb, bf16_t* __restrict__ wkb,
    bf16_t* __restrict__ wvb, bf16_t* __restrict__ wob,
    float2* __restrict__ tab) {
  const int bid = blockIdx.x;
  if (bid < 8192) {
    const float* src;
    bf16_t* dst;
    size_t base;
    if (bid < 4096) {
      src = x; dst = xb; base = (size_t)bid << 10;
    } else {
      int wsel = (bid - 4096) >> 10;
      src = wsel == 0 ? wq : wsel == 1 ? wk : wsel == 2 ? wv : wo;
      dst = wsel == 0 ? wqb : wsel == 1 ? wkb : wsel == 2 ? wvb : wob;
      base = (size_t)((bid - 4096) & 1023) << 10;
    }
    size_t i = base + (size_t)threadIdx.x * 4;
    float4 v = *(const float4*)(src + i);
    bf16x4 o = { (bf16_t)v.x, (bf16_t)v.y, (bf16_t)v.z, (bf16_t)v.w };
    *(bf16x4*)(dst + i) = o;
  } else {
    int i = (bid - 8192) * 256 + threadIdx.x;  // < S*32
    int s = i >> 5, d = i & 31;
    float th = (float)s * expf((float)d * -0.2878231366f);  // ln(10000)/32
    tab[i] = make_float2(cosf(th), sinf(th));
  }
}

// ---------------------------------------------------------------------------
// Fused QKV NT GEMM: M=4096, N=3072 (wq|wk|wv contiguous), K=1024.
// 128x64 tiles -> 1536 blocks (~5 blocks/CU). 4 waves x (2x4) MFMA (per-wave
// 32x64). BK=64 XOR-swizzled staging. z = n0g>>10 selects output:
// z=0 Q (rope, scale 0.125*log2e), z=1 K (rope), z=2 V (bias + transposed
// store into VT[bh][d][s], 4 consecutive s per bf16x4).
__global__ __launch_bounds__(256) void k_gemm_qkv(
    const bf16_t* __restrict__ A, const bf16_t* __restrict__ Wall,
    const float* __restrict__ c0, const float* __restrict__ c1,
    const float* __restrict__ c2, bf16_t* __restrict__ Oq,
    bf16_t* __restrict__ Ok, bf16_t* __restrict__ VTo,
    const float2* __restrict__ tab) {
  __shared__ __align__(16) bf16_t Al[128 * 64];
  __shared__ __align__(16) bf16_t Bl[64 * 64];
  const int t = threadIdx.x, w = t >> 6, l = t & 63;
  const int lr = l & 15, lc = l >> 4;
  const int lid = blockIdx.x;                     // 1536 blocks
  const int xcd = lid & 7, s = lid >> 3;          // s in [0,192)
  const int my = ((xcd >> 1) << 3) + (s & 7);     // [0,32)
  const int nx = (xcd & 1) * 24 + (s >> 3);       // [0,48)
  const int m0 = my * 128, n0g = nx * 64;
  const int z = n0g >> 10, n0l = n0g & 1023;
  f32x4 acc[2][4] = {};

  for (int k0 = 0; k0 < DIM; k0 += 64) {
    __syncthreads();
    // A: 128 rows x 8 chunks = 1024 (4 rounds); B: 64 rows x 8 = 512 (2)
#pragma unroll
    for (int ld = 0; ld < 4; ++ld) {
      int c = t + ld * 256;
      int row = c >> 3;
      int j = ((c & 7) ^ (row & 7)) << 3;
      gl_lds16(A + (size_t)(m0 + row) * DIM + k0 + j,
               Al + (size_t)(w * 64 + ld * 256) * 8);
    }
#pragma unroll
    for (int ld = 0; ld < 2; ++ld) {
      int c = t + ld * 256;
      int row = c >> 3;
      int j = ((c & 7) ^ (row & 7)) << 3;
      gl_lds16(Wall + (size_t)(n0g + row) * DIM + k0 + j,
               Bl + (size_t)(w * 64 + ld * 256) * 8);
    }
    asm volatile("s_waitcnt vmcnt(0)" ::: "memory");
    __syncthreads();
    bf16x8 af[2][2], bfr[2][4];
#pragma unroll
    for (int ks = 0; ks < 2; ++ks) {
#pragma unroll
      for (int mi = 0; mi < 2; ++mi) {
        int row = w * 32 + mi * 16 + lr;
        int off = ((ks * 4 + lc) << 4) ^ ((row & 7) << 4);
        af[ks][mi] = *(const bf16x8*)((const char*)Al + row * 128 + off);
      }
#pragma unroll
      for (int ni = 0; ni < 4; ++ni) {
        int row = ni * 16 + lr;
        int off = ((ks * 4 + lc) << 4) ^ ((row & 7) << 4);
        bfr[ks][ni] = *(const bf16x8*)((const char*)Bl + row * 128 + off);
      }
    }
    __builtin_amdgcn_s_setprio(1);
#pragma unroll
    for (int ks = 0; ks < 2; ++ks)
#pragma unroll
      for (int mi = 0; mi < 2; ++mi)
#pragma unroll
        for (int ni = 0; ni < 4; ++ni)
          acc[mi][ni] = mfma16(af[ks][mi], bfr[ks][ni], acc[mi][ni]);
    __builtin_amdgcn_s_setprio(0);
  }

  if (z == 2) {
    // V: bias + transposed store VT[bh][d][s], 4 consecutive s per bf16x4.
    const int h = n0l >> 6;                      // 64-col tile = one head
#pragma unroll
    for (int ni = 0; ni < 4; ++ni) {
      const int d = ni * 16 + lr;
      const float bv = c2[n0l + ni * 16 + lr];
#pragma unroll
      for (int mi = 0; mi < 2; ++mi) {
        int rowb = m0 + w * 32 + mi * 16 + lc * 4;
        int bb = rowb >> 11, ss = rowb & (S - 1);
        bf16x4 pb = { (bf16_t)(acc[mi][ni][0] + bv),
                      (bf16_t)(acc[mi][ni][1] + bv),
                      (bf16_t)(acc[mi][ni][2] + bv),
                      (bf16_t)(acc[mi][ni][3] + bv) };
        *(bf16x4*)(VTo + ((size_t)(bb * NH + h) * HD + d) * S + ss) = pb;
      }
    }
  } else {
    // Q/K: bias + rope. Pair partner = adjacent lr lane (col parity = lr
    // parity). p0 = pair index within head = (ni*16+lr)>>1.
    bf16_t* Ov = z == 0 ? Oq : Ok;
    const float* bias = z == 0 ? c0 : c1;
    const float scale = z == 0 ? 0.125f * 1.4426950408889634f : 1.0f;
#pragma unroll
    for (int ni = 0; ni < 4; ++ni) {
      const int col = n0l + ni * 16 + lr;
      const float bv = bias[col];
      const int p0 = ni * 8 + (lr >> 1);
#pragma unroll
      for (int mi = 0; mi < 2; ++mi) {
#pragma unroll
        for (int r = 0; r < 4; ++r) {
          int row = m0 + w * 32 + mi * 16 + lc * 4 + r;
          float v = acc[mi][ni][r] + bv;
          float pt = __shfl_xor(v, 1);
          float2 cs = tab[(row & (S - 1)) * 32 + p0];
          float out = (lr & 1) ? (pt * cs.y + v * cs.x)
                               : (v * cs.x - pt * cs.y);
          Ov[(size_t)row * DIM + col] = (bf16_t)(out * scale);
        }
      }
    }
  }
}

// ---------------------------------------------------------------------------
// Out projection: M=4096, N=1024, K=1024. 64x64 tiles -> 1024 blocks
// (4 blocks/CU). 4 waves x (1x4) MFMA (per-wave 16x64). fp32 + bias.
__global__ __launch_bounds__(256) void k_gemm_out(
    const bf16_t* __restrict__ A, const bf16_t* __restrict__ Bw,
    const float* __restrict__ bias, float* __restrict__ Ov) {
  __shared__ __align__(16) bf16_t Al[64 * 64];
  __shared__ __align__(16) bf16_t Bl[64 * 64];
  const int t = threadIdx.x, w = t >> 6, l = t & 63;
  const int lr = l & 15, lc = l >> 4;
  const int lid = blockIdx.x;                     // 1024 blocks
  const int xcd = lid & 7, s = lid >> 3;          // s in [0,128)
  const int my = ((xcd >> 1) << 4) + (s & 15);    // [0,64)
  const int nx = (xcd & 1) * 8 + (s >> 4);        // [0,16)
  const int m0 = my * 64, n0 = nx * 64;
  f32x4 acc[4] = {};

  for (int k0 = 0; k0 < DIM; k0 += 64) {
    __syncthreads();
    // A: 64 rows x 8 chunks = 512 (2 rounds); B same
#pragma unroll
    for (int ld = 0; ld < 2; ++ld) {
      int c = t + ld * 256;
      int row = c >> 3;
      int j = ((c & 7) ^ (row & 7)) << 3;
      gl_lds16(A + (size_t)(m0 + row) * DIM + k0 + j,
               Al + (size_t)(w * 64 + ld * 256) * 8);
    }
#pragma unroll
    for (int ld = 0; ld < 2; ++ld) {
      int c = t + ld * 256;
      int row = c >> 3;
      int j = ((c & 7) ^ (row & 7)) << 3;
      gl_lds16(Bw + (size_t)(n0 + row) * DIM + k0 + j,
               Bl + (size_t)(w * 64 + ld * 256) * 8);
    }
    asm volatile("s_waitcnt vmcnt(0)" ::: "memory");
    __syncthreads();
    bf16x8 af[2], bfr[2][4];
#pragma unroll
    for (int ks = 0; ks < 2; ++ks) {
      int arow = w * 16 + lr;
      int aoff = ((ks * 4 + lc) << 4) ^ ((arow & 7) << 4);
      af[ks] = *(const bf16x8*)((const char*)Al + arow * 128 + aoff);
#pragma unroll
      for (int ni = 0; ni < 4; ++ni) {
        int row = ni * 16 + lr;
        int off = ((ks * 4 + lc) << 4) ^ ((row & 7) << 4);
        bfr[ks][ni] = *(const bf16x8*)((const char*)Bl + row * 128 + off);
      }
    }
    __builtin_amdgcn_s_setprio(1);
#pragma unroll
    for (int ks = 0; ks < 2; ++ks)
#pragma unroll
      for (int ni = 0; ni < 4; ++ni)
        acc[ni] = mfma16(af[ks], bfr[ks][ni], acc[ni]);
    __builtin_amdgcn_s_setprio(0);
  }

#pragma unroll
  for (int ni = 0; ni < 4; ++ni) {
    int col = n0 + ni * 16 + lr;
    float bv = bias[col];
#pragma unroll
    for (int r = 0; r < 4; ++r) {
      int row = m0 + w * 16 + lc * 4 + r;
      Ov[(size_t)row * DIM + col] = acc[ni][r] + bv;
    }
  }
}

// ---------------------------------------------------------------------------
// Causal flash attention: KVBLK=64, one q-tile per block, grid 1024
// (4 blocks/CU), single-buffered sync staging, descending-size dispatch,
// swapped QK^T + exp2 softmax (log2e folded into Q rope scale), defer-max.
DEVFN void stage_kv(const bf16_t* __restrict__ Kc,
                    const bf16_t* __restrict__ VT, bf16_t* Kb, bf16_t* Vb,
                    int b, int bh, int h, int k0, int tid, int w) {
#pragma unroll
  for (int ld = 0; ld < 2; ++ld) {
    int c = tid + ld * 256;
    int row = c >> 3;
    int j = ((c & 7) ^ (row & 7)) << 3;  // pre-swizzled source chunk
    bf16_t* dstK = Kb + (size_t)(w * 64 + ld * 256) * 8;
    bf16_t* dstV = Vb + (size_t)(w * 64 + ld * 256) * 8;
    gl_lds16(Kc + (size_t)(b * S + k0 + row) * DIM + h * HD + j, dstK);
    gl_lds16(VT + ((size_t)bh * HD + row) * S + k0 + j, dstV);
  }
}

__global__ __launch_bounds__(256) void k_attn(const bf16_t* __restrict__ Q,
                                              const bf16_t* __restrict__ Kc,
                                              const bf16_t* __restrict__ VT,
                                              bf16_t* __restrict__ O) {
  __shared__ __align__(16) bf16_t Kl[64 * 64];
  __shared__ __align__(16) bf16_t Vl[64 * 64];
  __shared__ __align__(16) bf16_t Pl[4][16 * 64];
  const int tid = threadIdx.x, w = tid >> 6, l = tid & 63;
  const int lr = l & 15, lc = l >> 4;
  const int lid = blockIdx.x;
  const int xcd = lid & 7;
  const int rest = lid >> 3;          // 0..127
  const int t_ord = rest >> 2;        // 0..31
  const int hh = rest & 3;
  const int tile = 31 - t_ord;        // big tiles dispatch first
  const int bh = xcd * 4 + hh;
  const int b = bh >> 4, h = bh & 15;
  char* Pw = (char*)&Pl[w][0];

  const int q0 = tile * 64;
  const int nt = tile + 1;

  bf16x8 qf[2];
  {
    const bf16_t* qp =
        Q + (size_t)(b * S + q0 + w * 16 + lr) * DIM + h * HD + lc * 8;
    qf[0] = *(const bf16x8*)qp;
    qf[1] = *(const bf16x8*)(qp + 32);
  }
  f32x4 o[4] = {};
  float m_run = -INFINITY;
  float rowsum = 0.f;

#pragma unroll 1
  for (int it = 0; it < nt; ++it) {
    stage_kv(Kc, VT, &Kl[0], &Vl[0], b, bh, h, it * 64, tid, w);
    asm volatile("s_waitcnt vmcnt(0)" ::: "memory");
    __builtin_amdgcn_s_barrier();
    __builtin_amdgcn_sched_barrier(0);

    // swapped QK^T: lane (lr,lc) holds S'[q=w*16+lr][k=ni*16+lc*4+r]
    f32x4 s[4] = {};
    __builtin_amdgcn_s_setprio(1);
#pragma unroll
    for (int ks = 0; ks < 2; ++ks) {
#pragma unroll
      for (int ni = 0; ni < 4; ++ni) {
        int row = ni * 16 + lr;
        int off = (ks * 64 + lc * 16) ^ ((row & 7) << 4);
        bf16x8 kf = *(const bf16x8*)((const char*)Kl + row * 128 + off);
        s[ni] = mfma16(kf, qf[ks], s[ni]);
      }
    }
    __builtin_amdgcn_s_setprio(0);

    if (it == tile) {  // diagonal tile: mask k_local > q_local
      const int qloc = w * 16 + lr;
#pragma unroll
      for (int ni = 0; ni < 4; ++ni)
#pragma unroll
        for (int r = 0; r < 4; ++r)
          if (ni * 16 + lc * 4 + r > qloc) s[ni][r] = -INFINITY;
    }

    // row max: paired tree, then 2 cross-lane reduces
    float m01 = fmaxf(fmaxf(s[0][0], s[0][1]), fmaxf(s[0][2], s[0][3]));
    float m23 = fmaxf(fmaxf(s[1][0], s[1][1]), fmaxf(s[1][2], s[1][3]));
    float m45 = fmaxf(fmaxf(s[2][0], s[2][1]), fmaxf(s[2][2], s[2][3]));
    float m67 = fmaxf(fmaxf(s[3][0], s[3][1]), fmaxf(s[3][2], s[3][3]));
    float pm = fmaxf(fmaxf(m01, m23), fmaxf(m45, m67));
    pm = fmaxf(pm, __shfl_xor(pm, 16));
    pm = fmaxf(pm, __shfl_xor(pm, 32));

    // defer-max (log2 units): rescale only if max grew past 8 (P <= 2^8)
    if (__ballot(pm > m_run + 8.f)) {
      float mn = fmaxf(m_run, pm);
      float alpha = fast_exp2(m_run - mn);
      m_run = mn;
      rowsum *= alpha;
#pragma unroll
      for (int r = 0; r < 4; ++r) {
        float aq = __shfl(alpha, lc * 4 + r);
#pragma unroll
        for (int ni = 0; ni < 4; ++ni) o[ni][r] *= aq;
      }
    }

    // P = exp2(s - m_run); in-lane partial sum; pack to LDS as b64
    float rs = 0.f;
#pragma unroll
    for (int ni = 0; ni < 4; ++ni) {
      float p0 = fast_exp2(s[ni][0] - m_run);
      float p1 = fast_exp2(s[ni][1] - m_run);
      float p2 = fast_exp2(s[ni][2] - m_run);
      float p3 = fast_exp2(s[ni][3] - m_run);
      rs += (p0 + p1) + (p2 + p3);
      bf16x4 pb = { (bf16_t)p0, (bf16_t)p1, (bf16_t)p2, (bf16_t)p3 };
      *(bf16x4*)(Pw + (lr * 128 + ((ni * 32 + lc * 8) ^ ((lr & 7) << 4)))) =
          pb;
    }
    rs += __shfl_xor(rs, 16);
    rs += __shfl_xor(rs, 32);
    rowsum += rs;

    // PV: o[ni] += P(16x64) * V(64x64)
    __builtin_amdgcn_s_setprio(1);
#pragma unroll
    for (int ks = 0; ks < 2; ++ks) {
      int off = ks * 64 + lc * 16;
      bf16x8 pa = *(const bf16x8*)(Pw + lr * 128 + (off ^ ((lr & 7) << 4)));
#pragma unroll
      for (int ni = 0; ni < 4; ++ni) {
        int vrow = ni * 16 + lr;
        bf16x8 vb = *(const bf16x8*)((const char*)Vl + vrow * 128 +
                                     (off ^ ((vrow & 7) << 4)));
        o[ni] = mfma16(pa, vb, o[ni]);
      }
    }
    __builtin_amdgcn_s_setprio(0);

    __builtin_amdgcn_s_barrier();  // all reads done before next stage
  }

  // normalize + store. o[ni]: q = q0 + w*16 + lc*4 + r, d = ni*16 + lr
  float inv[4];
#pragma unroll
  for (int r = 0; r < 4; ++r) inv[r] = 1.0f / __shfl(rowsum, lc * 4 + r);
#pragma unroll
  for (int ni = 0; ni < 4; ++ni)
#pragma unroll
    for (int r = 0; r < 4; ++r) {
      int qr = q0 + w * 16 + lc * 4 + r;
      float v = o[ni][r] * inv[r];
      O[(size_t)(b * S + qr) * DIM + h * HD + ni * 16 + lr] = (bf16_t)v;
    }
}

// ---------------------------------------------------------------------------
extern "C" void kernel_launch(void* const* d_in, const int* in_sizes, int n_in,
                              void* d_out, int out_size, void* d_ws,
                              size_t ws_size, hipStream_t stream) {
  const float* x  = (const float*)d_in[0];
  const float* wq = (const float*)d_in[1];
  const float* bq = (const float*)d_in[2];
  const float* wk = (const float*)d_in[3];
  const float* bk = (const float*)d_in[4];
  const float* wv = (const float*)d_in[5];
  const float* bv = (const float*)d_in[6];
  const float* wo = (const float*)d_in[7];
  const float* bo = (const float*)d_in[8];

  const size_t MD = (size_t)Mrows * DIM;   // 4194304
  const size_t WD = (size_t)DIM * DIM;     // 1048576
  bf16_t* W = (bf16_t*)d_ws;
  bf16_t* x_bf  = W;
  bf16_t* wq_bf = x_bf + MD;               // wq|wk|wv contiguous = [3072][1024]
  bf16_t* wk_bf = wq_bf + WD;
  bf16_t* wv_bf = wk_bf + WD;
  bf16_t* wo_bf = wv_bf + WD;
  bf16_t* q_lin = wo_bf + WD;
  bf16_t* k_lin = q_lin + MD;
  bf16_t* v_lin = k_lin + MD;              // unused (kept for layout)
  bf16_t* vT    = v_lin + MD;
  float2* tab   = (float2*)(vT + MD);
  bf16_t* attn_out = x_bf;  // x_bf dead after k_gemm_qkv; rewritten by k_prep
                            // every call -> no cross-call state dependency

  k_prep<<<8448, 256, 0, stream>>>(x, wq, wk, wv, wo, x_bf, wq_bf, wk_bf,
                                   wv_bf, wo_bf, tab);

  // Q/K leave already roped (Q scaled 1/8*log2e); V leaves transposed in VT.
  k_gemm_qkv<<<1536, 256, 0, stream>>>(x_bf, wq_bf, bq, bk, bv, q_lin, k_lin,
                                       vT, tab);

  k_attn<<<1024, 256, 0, stream>>>(q_lin, k_lin, vT, attn_out);

  k_gemm_out<<<1024, 256, 0, stream>>>(attn_out, wo_bf, bo, (float*)d_out);
}